// Round 10
// baseline (355.182 us; speedup 1.0000x reference)
//
#include <hip/hip_runtime.h>
#include <hip/hip_bf16.h>
#include <math.h>

#define NN 2048
#define DA 256
#define DK 64
#define DG 64

typedef float f32x4 __attribute__((ext_vector_type(4)));

__device__ __forceinline__ float wave_reduce_max(float v) {
  #pragma unroll
  for (int o = 32; o >= 1; o >>= 1) v = fmaxf(v, __shfl_xor(v, o, 64));
  return v;
}
__device__ __forceinline__ float wave_reduce_sum(float v) {
  #pragma unroll
  for (int o = 32; o >= 1; o >>= 1) v += __shfl_xor(v, o, 64);
  return v;
}

// Allreduce-sum across each 16-lane group, pure VALU (DPP), no LDS pipe.
__device__ __forceinline__ float dpp_reduce16(float x) {
  int t;
  t = __builtin_amdgcn_update_dpp(0, __float_as_int(x), 0xB1, 0xF, 0xF, true);
  x += __int_as_float(t);
  t = __builtin_amdgcn_update_dpp(0, __float_as_int(x), 0x4E, 0xF, 0xF, true);
  x += __int_as_float(t);
  t = __builtin_amdgcn_update_dpp(0, __float_as_int(x), 0x124, 0xF, 0xF, true);
  x += __int_as_float(t);
  t = __builtin_amdgcn_update_dpp(0, __float_as_int(x), 0x128, 0xF, 0xF, true);
  x += __int_as_float(t);
  return x;
}

__device__ __forceinline__ float dot4(const f32x4 a, const f32x4 b) {
  float d = a.x * b.x;
  d = fmaf(a.y, b.y, d);
  d = fmaf(a.z, b.z, d);
  d = fmaf(a.w, b.w, d);
  return d;
}

// One block per row m: stage f_a row in LDS, 192 threads each compute one
// output element of {w_k, w_q, w_v}.
__global__ __launch_bounds__(256) void proj_kernel(
    const float* __restrict__ fa,
    const float* __restrict__ WKw, const float* __restrict__ WKb,
    const float* __restrict__ WQw, const float* __restrict__ WQb,
    const float* __restrict__ WVw, const float* __restrict__ WVb,
    float* __restrict__ wk, float* __restrict__ wq, float* __restrict__ wv)
{
  __shared__ float s_fa[DA];
  const int m = blockIdx.x, tid = threadIdx.x;
  s_fa[tid] = fa[(size_t)m * DA + tid];
  __syncthreads();
  if (tid < 192) {
    const int o = tid >> 6, k = tid & 63;
    const float* W = (o == 0 ? WKw : (o == 1 ? WQw : WVw)) + (size_t)k * DA;
    const float* B = (o == 0 ? WKb : (o == 1 ? WQb : WVb));
    float acc = B[k];
    const float4* W4 = (const float4*)W;
    const float4* F4 = (const float4*)s_fa;
    #pragma unroll 8
    for (int c = 0; c < DA / 4; ++c) {
      float4 w4 = W4[c], f4 = F4[c];
      acc = fmaf(w4.x, f4.x, acc); acc = fmaf(w4.y, f4.y, acc);
      acc = fmaf(w4.z, f4.z, acc); acc = fmaf(w4.w, f4.w, acc);
    }
    float* dst = (o == 0 ? wk : (o == 1 ? wq : wv));
    dst[(size_t)m * DK + k] = acc;
  }
}

// One block (256 threads = 4 waves) per output row m.
// Pre-pass: dq scores (wq L2 loads only) -> s_logit, pure stores.
// Hot loop: pe NT loads ONLY (homogeneous vmcnt queue) -> s_geo, pure stores.
// No barrier between them (wave-private n-ranges). Phase 2 folds the two
// arrays during max/exp; phase 3 as R3.
__global__ __launch_bounds__(256) void fused_kernel(
    const float* __restrict__ pe,
    const float* __restrict__ wgw, const float* __restrict__ wgb,
    const float* __restrict__ wk, const float* __restrict__ wq,
    const float* __restrict__ wv,
    float* __restrict__ out)
{
  __shared__ float s_logit[NN];          // 8 KB: dq scores -> probs
  __shared__ float s_geo[NN];            // 8 KB: log geometric term
  __shared__ float s_rmax[4], s_rsum[4];
  __shared__ float s_pacc[4][4][DK];     // 4 KB partial accumulators

  const int m = blockIdx.x, tid = threadIdx.x;
  const int wave = tid >> 6, lane = tid & 63;
  const int sub = lane >> 4;             // n within the 4-n chunk
  const int c4  = lane & 15;             // float4 chunk within 64 floats

  // loop-invariant per-lane slices
  const f32x4 wg4 = ((const f32x4*)wgw)[c4];
  const f32x4 wk4 = ((const f32x4*)(wk + (size_t)m * DK))[c4];
  const float gb = wgb[0];
  const int n0 = wave * (NN / 4);

  // ---- pre-pass: dq scores, wq loads only (L2) ----
  #pragma unroll 4
  for (int it = 0; it < (NN / 4) / 4; ++it) {   // 128 iters, 4 n's each
    const int nb = n0 + it * 4;
    const f32x4 q = ((const f32x4*)(wq + (size_t)nb * DK))[lane];
    float dq = dot4(q, wk4);
    dq = dpp_reduce16(dq);
    if (c4 == 0) s_logit[nb + sub] = dq * 0.125f;
  }

  // ---- hot loop: pe stream only (NT), homogeneous queue ----
  #pragma unroll 4
  for (int it = 0; it < (NN / 4) / 4; ++it) {   // 128 iters, 4 n's each
    const int nb = n0 + it * 4;
    const f32x4 p = __builtin_nontemporal_load(
        (const f32x4*)(pe + ((size_t)m * NN + nb) * DG) + lane);
    float dg = dot4(p, wg4);
    dg = dpp_reduce16(dg);
    if (c4 == 0) {
      // relu -> clip(1e-6) -> log  ==  log(max(x, 1e-6))
      s_geo[nb + sub] = __logf(fmaxf(dg + gb, 1e-6f));
    }
  }
  __syncthreads();

  // ---- phase 2: max, exp, sum over (s_logit + s_geo) ----
  float mx = -INFINITY;
  #pragma unroll
  for (int i = 0; i < NN / 256; ++i) {
    const int n = i * 256 + tid;
    mx = fmaxf(mx, s_logit[n] + s_geo[n]);
  }
  mx = wave_reduce_max(mx);
  if (lane == 0) s_rmax[wave] = mx;
  __syncthreads();
  const float rmax = fmaxf(fmaxf(s_rmax[0], s_rmax[1]), fmaxf(s_rmax[2], s_rmax[3]));
  float lsum = 0.f;
  #pragma unroll
  for (int i = 0; i < NN / 256; ++i) {
    const int n = i * 256 + tid;
    const float p = __expf(s_logit[n] + s_geo[n] - rmax);
    s_logit[n] = p;
    lsum += p;
  }
  lsum = wave_reduce_sum(lsum);
  if (lane == 0) s_rsum[wave] = lsum;
  __syncthreads();
  const float inv = 1.0f / (s_rsum[0] + s_rsum[1] + s_rsum[2] + s_rsum[3]);

  // ---- phase 3: out[m,:] = p-row @ w_v, float4 loads ----
  f32x4 acc = {0.f, 0.f, 0.f, 0.f};
  #pragma unroll 8
  for (int it = 0; it < (NN / 4) / 4; ++it) {
    const int nb = n0 + it * 4;
    const float pb = s_logit[nb + sub];
    const f32x4 v = ((const f32x4*)(wv + (size_t)(nb + sub) * DK))[c4];
    acc.x = fmaf(pb, v.x, acc.x);
    acc.y = fmaf(pb, v.y, acc.y);
    acc.z = fmaf(pb, v.z, acc.z);
    acc.w = fmaf(pb, v.w, acc.w);
  }
  ((f32x4*)&s_pacc[wave][sub][0])[c4] = acc;
  __syncthreads();
  if (tid < DK) {
    float r = 0.f;
    #pragma unroll
    for (int w = 0; w < 4; ++w)
      #pragma unroll
      for (int s = 0; s < 4; ++s)
        r += s_pacc[w][s][tid];
    out[(size_t)m * DK + tid] = r * inv;
  }
}

extern "C" void kernel_launch(void* const* d_in, const int* in_sizes, int n_in,
                              void* d_out, int out_size, void* d_ws, size_t ws_size,
                              hipStream_t stream) {
  const float* fa  = (const float*)d_in[0];
  const float* pe  = (const float*)d_in[1];
  const float* wgw = (const float*)d_in[2];
  const float* wgb = (const float*)d_in[3];
  const float* wkw = (const float*)d_in[4];
  const float* wkb = (const float*)d_in[5];
  const float* wqw = (const float*)d_in[6];
  const float* wqb = (const float*)d_in[7];
  const float* wvw = (const float*)d_in[8];
  const float* wvb = (const float*)d_in[9];
  float* out = (float*)d_out;

  float* wk = (float*)d_ws;          // [NN, DK]
  float* wq = wk + (size_t)NN * DK;  // [NN, DK]
  float* wv = wq + (size_t)NN * DK;  // [NN, DK]

  proj_kernel<<<NN, 256, 0, stream>>>(fa, wkw, wkb, wqw, wqb, wvw, wvb, wk, wq, wv);
  fused_kernel<<<NN, 256, 0, stream>>>(pe, wgw, wgb, wk, wq, wv, out);
}

// Round 11
// 299.939 us; speedup vs baseline: 1.1842x; 1.1842x over previous
//
#include <hip/hip_runtime.h>
#include <hip/hip_bf16.h>
#include <math.h>

#define NN 2048
#define DA 256
#define DK 64
#define DG 64

typedef float f32x4 __attribute__((ext_vector_type(4)));

__device__ __forceinline__ float wave_reduce_max(float v) {
  #pragma unroll
  for (int o = 32; o >= 1; o >>= 1) v = fmaxf(v, __shfl_xor(v, o, 64));
  return v;
}
__device__ __forceinline__ float wave_reduce_sum(float v) {
  #pragma unroll
  for (int o = 32; o >= 1; o >>= 1) v += __shfl_xor(v, o, 64);
  return v;
}

// Allreduce-sum across each 16-lane group, pure VALU (DPP), no LDS pipe.
__device__ __forceinline__ float dpp_reduce16(float x) {
  int t;
  t = __builtin_amdgcn_update_dpp(0, __float_as_int(x), 0xB1, 0xF, 0xF, true);
  x += __int_as_float(t);
  t = __builtin_amdgcn_update_dpp(0, __float_as_int(x), 0x4E, 0xF, 0xF, true);
  x += __int_as_float(t);
  t = __builtin_amdgcn_update_dpp(0, __float_as_int(x), 0x124, 0xF, 0xF, true);
  x += __int_as_float(t);
  t = __builtin_amdgcn_update_dpp(0, __float_as_int(x), 0x128, 0xF, 0xF, true);
  x += __int_as_float(t);
  return x;
}

__device__ __forceinline__ float dot4(const f32x4 a, const f32x4 b) {
  float d = a.x * b.x;
  d = fmaf(a.y, b.y, d);
  d = fmaf(a.z, b.z, d);
  d = fmaf(a.w, b.w, d);
  return d;
}

// Direct global->LDS DMA, 16B per lane: lane l's 16B from gp+l*16 lands at
// LDS base + l*16 (wave-uniform base, per-lane global src).
__device__ __forceinline__ void stage16(const float* gp, float* lp) {
  __builtin_amdgcn_global_load_lds(
      (const __attribute__((address_space(1))) void*)gp,
      (__attribute__((address_space(3))) void*)lp, 16, 0, 0);
}

// One block per row m: stage f_a row in LDS, 192 threads each compute one
// output element of {w_k, w_q, w_v}.
__global__ __launch_bounds__(256) void proj_kernel(
    const float* __restrict__ fa,
    const float* __restrict__ WKw, const float* __restrict__ WKb,
    const float* __restrict__ WQw, const float* __restrict__ WQb,
    const float* __restrict__ WVw, const float* __restrict__ WVb,
    float* __restrict__ wk, float* __restrict__ wq, float* __restrict__ wv)
{
  __shared__ float s_fa[DA];
  const int m = blockIdx.x, tid = threadIdx.x;
  s_fa[tid] = fa[(size_t)m * DA + tid];
  __syncthreads();
  if (tid < 192) {
    const int o = tid >> 6, k = tid & 63;
    const float* W = (o == 0 ? WKw : (o == 1 ? WQw : WVw)) + (size_t)k * DA;
    const float* B = (o == 0 ? WKb : (o == 1 ? WQb : WVb));
    float acc = B[k];
    const float4* W4 = (const float4*)W;
    const float4* F4 = (const float4*)s_fa;
    #pragma unroll 8
    for (int c = 0; c < DA / 4; ++c) {
      float4 w4 = W4[c], f4 = F4[c];
      acc = fmaf(w4.x, f4.x, acc); acc = fmaf(w4.y, f4.y, acc);
      acc = fmaf(w4.z, f4.z, acc); acc = fmaf(w4.w, f4.w, acc);
    }
    float* dst = (o == 0 ? wk : (o == 1 ? wq : wv));
    dst[(size_t)m * DK + k] = acc;
  }
}

// One block (256 threads = 4 waves) per output row m.
// Phase 1: pe+wq streamed via global_load_lds (width 16) into per-wave
//          double-buffered LDS tiles; counted s_waitcnt vmcnt(2) (never 0
//          in-loop); compute from LDS via ds_read_b128; no in-loop barriers
//          (wave-private buffers + n-ranges).
// Phase 2: block softmax in LDS. Phase 3: wv float4 loads (R3 structure).
__global__ __launch_bounds__(256) void fused_kernel(
    const float* __restrict__ pe,
    const float* __restrict__ wgw, const float* __restrict__ wgb,
    const float* __restrict__ wk, const float* __restrict__ wq,
    const float* __restrict__ wv,
    float* __restrict__ out)
{
  __shared__ float s_logit[NN];          // 8 KB: logits, then probs
  __shared__ float s_pe[4][2][256];      // 8 KB: per-wave dbuf pe tiles
  __shared__ float s_q[4][2][256];       // 8 KB: per-wave dbuf wq tiles
  __shared__ float s_rmax[4], s_rsum[4];
  __shared__ float s_pacc[4][4][DK];     // 4 KB partial accumulators

  const int m = blockIdx.x, tid = threadIdx.x;
  const int wave = tid >> 6, lane = tid & 63;
  const int sub = lane >> 4;             // n within the 4-n tile
  const int c4  = lane & 15;             // float4 chunk within 64 floats

  // loop-invariant per-lane slices
  const f32x4 wg4 = ((const f32x4*)wgw)[c4];
  const f32x4 wk4 = ((const f32x4*)(wk + (size_t)m * DK))[c4];
  const float gb = wgb[0];
  const int n0 = wave * (NN / 4);        // 512 n's per wave = 128 tiles of 4

  const float* pew = pe + ((size_t)m * NN + n0) * DG;  // wave's pe base
  const float* qw  = wq + (size_t)n0 * DK;             // wave's wq base

  // ---- phase 1: DMA-staged stream ----
  float lmax = -INFINITY;
  // prologue: stage tile 0 into buf 0
  stage16(pew + lane * 4, &s_pe[wave][0][0]);
  stage16(qw  + lane * 4, &s_q[wave][0][0]);
  #pragma unroll 2
  for (int t = 0; t < 127; ++t) {
    const int cur = t & 1, nxt = cur ^ 1;
    stage16(pew + (size_t)(t + 1) * 256 + lane * 4, &s_pe[wave][nxt][0]);
    stage16(qw  + (size_t)(t + 1) * 256 + lane * 4, &s_q[wave][nxt][0]);
    asm volatile("s_waitcnt vmcnt(2)" ::: "memory");  // tile t landed
    __builtin_amdgcn_sched_barrier(0);
    const f32x4 p = ((const f32x4*)&s_pe[wave][cur][0])[lane];
    const f32x4 q = ((const f32x4*)&s_q[wave][cur][0])[lane];
    float dg = dot4(p, wg4);
    float dq = dot4(q, wk4);
    dg = dpp_reduce16(dg);
    dq = dpp_reduce16(dq);
    if (c4 == 0) {
      // relu -> clip(1e-6) -> log  ==  log(max(x, 1e-6))
      const float logit = __logf(fmaxf(dg + gb, 1e-6f)) + dq * 0.125f;
      s_logit[n0 + t * 4 + sub] = logit;
      lmax = fmaxf(lmax, logit);
    }
  }
  asm volatile("s_waitcnt vmcnt(0)" ::: "memory");    // last tile (127) landed
  __builtin_amdgcn_sched_barrier(0);
  {
    const f32x4 p = ((const f32x4*)&s_pe[wave][1][0])[lane];   // 127 & 1
    const f32x4 q = ((const f32x4*)&s_q[wave][1][0])[lane];
    float dg = dot4(p, wg4);
    float dq = dot4(q, wk4);
    dg = dpp_reduce16(dg);
    dq = dpp_reduce16(dq);
    if (c4 == 0) {
      const float logit = __logf(fmaxf(dg + gb, 1e-6f)) + dq * 0.125f;
      s_logit[n0 + 127 * 4 + sub] = logit;
      lmax = fmaxf(lmax, logit);
    }
  }
  lmax = wave_reduce_max(lmax);
  if (lane == 0) s_rmax[wave] = lmax;
  __syncthreads();
  const float rmax = fmaxf(fmaxf(s_rmax[0], s_rmax[1]), fmaxf(s_rmax[2], s_rmax[3]));

  // ---- phase 2: exp + sum ----
  float lsum = 0.f;
  #pragma unroll
  for (int i = 0; i < NN / 256; ++i) {
    const int n = i * 256 + tid;
    const float p = __expf(s_logit[n] - rmax);
    s_logit[n] = p;
    lsum += p;
  }
  lsum = wave_reduce_sum(lsum);
  if (lane == 0) s_rsum[wave] = lsum;
  __syncthreads();
  const float inv = 1.0f / (s_rsum[0] + s_rsum[1] + s_rsum[2] + s_rsum[3]);

  // ---- phase 3: out[m,:] = p-row @ w_v, float4 loads ----
  f32x4 acc = {0.f, 0.f, 0.f, 0.f};
  #pragma unroll 4
  for (int it = 0; it < (NN / 4) / 4; ++it) {
    const int nb = n0 + it * 4;
    const float pb = s_logit[nb + sub];
    const f32x4 v = ((const f32x4*)(wv + (size_t)(nb + sub) * DK))[c4];
    acc.x = fmaf(pb, v.x, acc.x);
    acc.y = fmaf(pb, v.y, acc.y);
    acc.z = fmaf(pb, v.z, acc.z);
    acc.w = fmaf(pb, v.w, acc.w);
  }
  ((f32x4*)&s_pacc[wave][sub][0])[c4] = acc;
  __syncthreads();
  if (tid < DK) {
    float r = 0.f;
    #pragma unroll
    for (int w = 0; w < 4; ++w)
      #pragma unroll
      for (int s = 0; s < 4; ++s)
        r += s_pacc[w][s][tid];
    out[(size_t)m * DK + tid] = r * inv;
  }
}

extern "C" void kernel_launch(void* const* d_in, const int* in_sizes, int n_in,
                              void* d_out, int out_size, void* d_ws, size_t ws_size,
                              hipStream_t stream) {
  const float* fa  = (const float*)d_in[0];
  const float* pe  = (const float*)d_in[1];
  const float* wgw = (const float*)d_in[2];
  const float* wgb = (const float*)d_in[3];
  const float* wkw = (const float*)d_in[4];
  const float* wkb = (const float*)d_in[5];
  const float* wqw = (const float*)d_in[6];
  const float* wqb = (const float*)d_in[7];
  const float* wvw = (const float*)d_in[8];
  const float* wvb = (const float*)d_in[9];
  float* out = (float*)d_out;

  float* wk = (float*)d_ws;          // [NN, DK]
  float* wq = wk + (size_t)NN * DK;  // [NN, DK]
  float* wv = wq + (size_t)NN * DK;  // [NN, DK]

  proj_kernel<<<NN, 256, 0, stream>>>(fa, wkw, wkb, wqw, wqb, wvw, wvb, wk, wq, wv);
  fused_kernel<<<NN, 256, 0, stream>>>(pe, wgw, wgb, wk, wq, wv, out);
}